// Round 1
// baseline (375.478 us; speedup 1.0000x reference)
//
#include <hip/hip_runtime.h>

// MovingAvgNorm: sliding window (k=100, reflect pad 50/49) mean/std normalize
// x: (32, 16384, 80) fp32 -> out same shape fp32.
// Running-sum formulation: per (b, d-quad, time-chunk) thread, build initial
// window sum/sumsq over 100 rows, then slide: add x[refl(t+50)], sub x[refl(t-50)].

namespace {

constexpr int K     = 100;
constexpr int HALF  = 50;        // k/2 ; left pad = 50, right pad = 49
constexpr int Tn    = 16384;
constexpr int Dn    = 80;
constexpr int DQ    = Dn / 4;    // 20 float4 per (b,t) row
constexpr int Bn    = 32;
constexpr int CT    = 64;        // time steps per thread
constexpr int NCHUNK = Tn / CT;  // 256
constexpr float C1  = 1.0f / (float)K;
constexpr float C2  = 1.0f / (float)(K - 1);

__device__ __forceinline__ float fast_rsqrt(float v) {
#if __has_builtin(__builtin_amdgcn_rsqf)
  return __builtin_amdgcn_rsqf(v);   // v_rsq_f32, ~1 ulp
#else
  return __frsqrt_rn(v);
#endif
}

__global__ __launch_bounds__(256) void man_kernel(const float4* __restrict__ x,
                                                  float4* __restrict__ out) {
  int gid   = blockIdx.x * 256 + threadIdx.x;
  int dq    = gid % DQ;              // fastest: consecutive lanes -> contiguous 16B
  int rest  = gid / DQ;
  int chunk = rest % NCHUNK;
  int b     = rest / NCHUNK;
  if (b >= Bn) return;

  const float4* __restrict__ xb = x   + (size_t)b * Tn * DQ + dq;
  float4*       __restrict__ ob = out + (size_t)b * Tn * DQ + dq;

  const int t0 = chunk * CT;

  // Initial window for output t0: original time indices [t0-50, t0+49], reflected.
  float s1x = 0.f, s1y = 0.f, s1z = 0.f, s1w = 0.f;
  float s2x = 0.f, s2y = 0.f, s2z = 0.f, s2w = 0.f;
#pragma unroll 4
  for (int j = t0 - HALF; j < t0 + HALF; ++j) {
    int r = j;
    r = (r < 0) ? -r : r;                    // left reflect (no edge repeat)
    r = (r >= Tn) ? 2 * (Tn - 1) - r : r;    // right reflect
    float4 v = xb[r * DQ];
    s1x += v.x; s1y += v.y; s1z += v.z; s1w += v.w;
    s2x = fmaf(v.x, v.x, s2x); s2y = fmaf(v.y, v.y, s2y);
    s2z = fmaf(v.z, v.z, s2z); s2w = fmaf(v.w, v.w, s2w);
  }

#pragma unroll 2
  for (int t = t0; t < t0 + CT; ++t) {
    float4 xc = xb[t * DQ];

    int ja = t + HALF;                        // next row entering the window
    ja = (ja >= Tn) ? 2 * (Tn - 1) - ja : ja;
    int js = t - HALF;                        // oldest row leaving the window
    js = (js < 0) ? -js : js;
    float4 va = xb[ja * DQ];
    float4 vs = xb[js * DQ];

    float4 o;
    {
      float m   = s1x * C1;
      float var = fmaf(-s1x, m, s2x) * C2;
      float rr  = fast_rsqrt(fmaxf(var, 1e-30f));
      o.x = (xc.x - m) * rr;
    }
    {
      float m   = s1y * C1;
      float var = fmaf(-s1y, m, s2y) * C2;
      float rr  = fast_rsqrt(fmaxf(var, 1e-30f));
      o.y = (xc.y - m) * rr;
    }
    {
      float m   = s1z * C1;
      float var = fmaf(-s1z, m, s2z) * C2;
      float rr  = fast_rsqrt(fmaxf(var, 1e-30f));
      o.z = (xc.z - m) * rr;
    }
    {
      float m   = s1w * C1;
      float var = fmaf(-s1w, m, s2w) * C2;
      float rr  = fast_rsqrt(fmaxf(var, 1e-30f));
      o.w = (xc.w - m) * rr;
    }
    ob[t * DQ] = o;

    // Slide window: [t-50, t+49] -> [t-49, t+50]
    s1x += va.x - vs.x; s1y += va.y - vs.y;
    s1z += va.z - vs.z; s1w += va.w - vs.w;
    s2x = fmaf(va.x, va.x, s2x); s2x = fmaf(-vs.x, vs.x, s2x);
    s2y = fmaf(va.y, va.y, s2y); s2y = fmaf(-vs.y, vs.y, s2y);
    s2z = fmaf(va.z, va.z, s2z); s2z = fmaf(-vs.z, vs.z, s2z);
    s2w = fmaf(va.w, va.w, s2w); s2w = fmaf(-vs.w, vs.w, s2w);
  }
}

}  // namespace

extern "C" void kernel_launch(void* const* d_in, const int* in_sizes, int n_in,
                              void* d_out, int out_size, void* d_ws, size_t ws_size,
                              hipStream_t stream) {
  (void)in_sizes; (void)n_in; (void)out_size; (void)d_ws; (void)ws_size;
  const float4* x = (const float4*)d_in[0];
  float4* o = (float4*)d_out;
  constexpr int total  = Bn * NCHUNK * DQ;     // 32 * 256 * 20 = 163840 threads
  constexpr int blocks = total / 256;          // 640
  man_kernel<<<blocks, 256, 0, stream>>>(x, o);
}

// Round 2
// 300.626 us; speedup vs baseline: 1.2490x; 1.2490x over previous
//
#include <hip/hip_runtime.h>

// MovingAvgNorm, LDS-tiled: x (32,16384,80) fp32, window k=100 reflect-padded.
// Block owns (batch, 512-step time chunk, one of 5 groups of 16 float channels).
// Phase A: stage 612x64B tile to LDS (float4 loads). Phase B: 8-row chunk sums
// in LDS. Phase C: each thread inits its window from 12 chunk sums + 4 rows,
// then slides over 8 outputs (add/sub/center reads from LDS).

namespace {

constexpr int K    = 100;
constexpr int HALF = 50;
constexpr int Tn   = 16384;
constexpr int Bn   = 32;
constexpr int DGn  = 5;            // D=80 floats -> 5 groups of 8 float2
constexpr int GC   = 8;            // float2 columns per group (16 floats, 64 B)
constexpr int ROWF2 = 40;          // float2 per full row (80 floats)
constexpr int CTB  = 512;          // time steps per block
constexpr int NTC  = Tn / CTB;     // 32 time chunks
constexpr int TILE = CTB + K;      // 612 staged rows
constexpr int CTT  = 8;            // outputs per thread
constexpr int TTn  = CTB / CTT;    // 64 time-threads
constexpr int BLK  = TTn * GC;     // 512 threads
constexpr int NCH  = 75;           // full 8-row chunks needed (q = tt..tt+11, tt<=63)
constexpr float C1 = 1.0f / (float)K;
constexpr float C2 = 1.0f / (float)(K - 1);

__device__ __forceinline__ float fast_rsqrt(float v) {
#if __has_builtin(__builtin_amdgcn_rsqf)
  return __builtin_amdgcn_rsqf(v);
#else
  return __frsqrt_rn(v);
#endif
}

__global__ __launch_bounds__(BLK) void man_kernel(const float2* __restrict__ x,
                                                  float2* __restrict__ out) {
  // 64 B rows, no pad: tt-lane-groups alias banks (structural for b64), but
  // total LDS issue (~40 reads/thread) stays well under the HBM-bound time.
  __shared__ float2 tile[TILE * GC];   // 39168 B
  __shared__ float2 c1s[NCH * GC];     // 4800 B
  __shared__ float2 c2s[NCH * GC];     // 4800 B  -> 48768 B total, 3 blocks/CU

  const int tid = threadIdx.x;
  const int blk = blockIdx.x;
  const int g   = blk % DGn;
  const int tc  = (blk / DGn) % NTC;
  const int b   = blk / (DGn * NTC);

  const int t0 = tc * CTB;
  const float2* __restrict__ xb = x   + (size_t)b * Tn * ROWF2 + g * GC;
  float2*       __restrict__ ob = out + (size_t)b * Tn * ROWF2 + g * GC;

  // ---- Phase A: stage tile rows [t0-50, t0-50+612) with reflect, float4 ----
  for (int w = tid; w < TILE * GC / 2; w += BLK) {   // 2448 float4
    int r  = w >> 2;
    int c4 = w & 3;
    int gr = t0 - HALF + r;
    gr = (gr < 0) ? -gr : gr;
    gr = (gr >= Tn) ? 2 * (Tn - 1) - gr : gr;
    float4 v = *(const float4*)(xb + (size_t)gr * ROWF2 + c4 * 2);
    *(float4*)(&tile[r * GC + c4 * 2]) = v;
  }
  __syncthreads();

  // ---- Phase B: 8-row chunk sums (s1, s2) for chunks q in [0, 75) ----
  {
    const int c = tid & (GC - 1);
    for (int q = tid >> 3; q < NCH; q += BLK / GC) {
      float s1x = 0.f, s1y = 0.f, s2x = 0.f, s2y = 0.f;
#pragma unroll
      for (int k = 0; k < CTT; ++k) {
        float2 v = tile[(q * CTT + k) * GC + c];
        s1x += v.x; s1y += v.y;
        s2x = fmaf(v.x, v.x, s2x); s2y = fmaf(v.y, v.y, s2y);
      }
      c1s[q * GC + c] = make_float2(s1x, s1y);
      c2s[q * GC + c] = make_float2(s2x, s2y);
    }
  }
  __syncthreads();

  // ---- Phase C: init window [tt*8, tt*8+100) from 12 chunks + 4 rows ----
  const int dq2 = tid & (GC - 1);
  const int tt  = tid >> 3;

  float s1x = 0.f, s1y = 0.f, s2x = 0.f, s2y = 0.f;
#pragma unroll
  for (int j = 0; j < 12; ++j) {
    float2 a  = c1s[(tt + j) * GC + dq2];
    float2 bb = c2s[(tt + j) * GC + dq2];
    s1x += a.x;  s1y += a.y;
    s2x += bb.x; s2y += bb.y;
  }
#pragma unroll
  for (int k = 0; k < 4; ++k) {
    float2 v = tile[(tt * CTT + 96 + k) * GC + dq2];
    s1x += v.x; s1y += v.y;
    s2x = fmaf(v.x, v.x, s2x); s2y = fmaf(v.y, v.y, s2y);
  }

  // ---- slide over 8 outputs ----
  const int rc0 = HALF + tt * CTT;       // tile-relative center row of output 0
#pragma unroll
  for (int i = 0; i < CTT; ++i) {
    const int rc = rc0 + i;
    float2 xc = tile[rc * GC + dq2];
    float2 va = tile[(rc + HALF) * GC + dq2];
    float2 vs = tile[(rc - HALF) * GC + dq2];

    float2 o;
    {
      float m   = s1x * C1;
      float var = fmaf(-s1x, m, s2x) * C2;
      float rr  = fast_rsqrt(fmaxf(var, 1e-30f));
      o.x = (xc.x - m) * rr;
    }
    {
      float m   = s1y * C1;
      float var = fmaf(-s1y, m, s2y) * C2;
      float rr  = fast_rsqrt(fmaxf(var, 1e-30f));
      o.y = (xc.y - m) * rr;
    }
    ob[(size_t)(t0 + tt * CTT + i) * ROWF2 + dq2] = o;

    s1x += va.x - vs.x;
    s1y += va.y - vs.y;
    s2x = fmaf(va.x, va.x, s2x); s2x = fmaf(-vs.x, vs.x, s2x);
    s2y = fmaf(va.y, va.y, s2y); s2y = fmaf(-vs.y, vs.y, s2y);
  }
}

}  // namespace

extern "C" void kernel_launch(void* const* d_in, const int* in_sizes, int n_in,
                              void* d_out, int out_size, void* d_ws, size_t ws_size,
                              hipStream_t stream) {
  (void)in_sizes; (void)n_in; (void)out_size; (void)d_ws; (void)ws_size;
  const float2* x = (const float2*)d_in[0];
  float2* o = (float2*)d_out;
  constexpr int blocks = Bn * NTC * DGn;   // 32*32*5 = 5120
  man_kernel<<<blocks, BLK, 0, stream>>>(x, o);
}

// Round 3
// 300.055 us; speedup vs baseline: 1.2514x; 1.0019x over previous
//
#include <hip/hip_runtime.h>

// MovingAvgNorm, LDS-tiled column-major: x (32,16384,80) fp32, k=100 reflect.
// Block = (batch, 512-step chunk, one of 5 groups of 16 channels), 512 threads.
// tile is COLUMN-major (tile[c][row], stride TILEP=614) so Phase C's three
// 8-row streams and the chunk sums are all ds_read_b128, bank-conflict-free
// (2*614 % 32 == 12, 4*77 % 32 == 20 spread start banks across channels).

namespace {

constexpr int K     = 100;
constexpr int HALF  = 50;
constexpr int Tn    = 16384;
constexpr int Bn    = 32;
constexpr int DGn   = 5;            // 5 groups of 8 float2 (16 floats)
constexpr int GC    = 8;            // float2 columns per group
constexpr int ROWF2 = 40;           // float2 per full 80-float row
constexpr int CTB   = 512;          // time steps per block
constexpr int NTC   = Tn / CTB;     // 32
constexpr int TILE  = CTB + K;      // 612 staged rows
constexpr int TILEP = 614;          // column stride (pad): 2*614 % 32 == 12
constexpr int CTT   = 8;            // outputs per thread
constexpr int TTn   = CTB / CTT;    // 64
constexpr int BLK   = TTn * GC;     // 512 threads
constexpr int NCH   = 75;           // 8-row chunk sums
constexpr int NCHP  = 77;           // chunk stride (pad): 4*77 % 32 == 20
constexpr float C1  = 1.0f / (float)K;
constexpr float C2  = 1.0f / (float)(K - 1);

__device__ __forceinline__ float fast_rsqrt(float v) {
#if __has_builtin(__builtin_amdgcn_rsqf)
  return __builtin_amdgcn_rsqf(v);
#else
  return __frsqrt_rn(v);
#endif
}

__global__ __launch_bounds__(BLK, 6) void man_kernel(const float2* __restrict__ x,
                                                     float2* __restrict__ out) {
  __shared__ __align__(16) float2 tile[GC * TILEP];  // 39296 B
  __shared__ float4 cs[GC * NCHP];                   // 9856 B -> 49152 B total, 3 blk/CU

  const int tid = threadIdx.x;
  const int blk = blockIdx.x;
  const int g   = blk % DGn;
  const int tc  = (blk / DGn) % NTC;
  const int b   = blk / (DGn * NTC);
  const int t0  = tc * CTB;

  const float2* __restrict__ xb = x   + (size_t)b * Tn * ROWF2 + g * GC;
  float2*       __restrict__ ob = out + (size_t)b * Tn * ROWF2 + g * GC;

  // ---- Phase A: stage rows [t0-50, t0+562) reflected; float4 global loads,
  //      transpose into column-major LDS via two b64 writes (bank-optimal). ----
  for (int w = tid; w < TILE * 4; w += BLK) {        // 2448 float4 jobs
    int r  = w >> 2;
    int c4 = w & 3;
    int gr = t0 - HALF + r;
    gr = (gr < 0) ? -gr : gr;
    gr = (gr >= Tn) ? 2 * (Tn - 1) - gr : gr;
    float4 v = *(const float4*)(xb + (size_t)gr * ROWF2 + c4 * 2);
    tile[(2 * c4)     * TILEP + r] = make_float2(v.x, v.y);
    tile[(2 * c4 + 1) * TILEP + r] = make_float2(v.z, v.w);
  }
  __syncthreads();

  // ---- Phase B: 8-row chunk sums, stored as float4(s1x,s1y,s2x,s2y) ----
  for (int job = tid; job < NCH * GC; job += BLK) {  // 600 jobs
    int c = job & 7;
    int q = job >> 3;
    const float4* tp = (const float4*)(tile + c * TILEP + q * 8);
    float s1x = 0.f, s1y = 0.f, s2x = 0.f, s2y = 0.f;
#pragma unroll
    for (int m = 0; m < 4; ++m) {
      float4 v = tp[m];                              // rows q*8+2m, q*8+2m+1
      s1x += v.x + v.z; s1y += v.y + v.w;
      s2x = fmaf(v.x, v.x, s2x); s2x = fmaf(v.z, v.z, s2x);
      s2y = fmaf(v.y, v.y, s2y); s2y = fmaf(v.w, v.w, s2y);
    }
    cs[c * NCHP + q] = make_float4(s1x, s1y, s2x, s2y);
  }
  __syncthreads();

  // ---- Phase C: init window [tt*8, tt*8+100) = 12 chunks + 4 rows, slide 8 ----
  const int c  = tid & 7;
  const int tt = tid >> 3;

  float s1x = 0.f, s1y = 0.f, s2x = 0.f, s2y = 0.f;
  const float4* cp = cs + c * NCHP + tt;
#pragma unroll
  for (int j = 0; j < 12; ++j) {
    float4 a = cp[j];
    s1x += a.x; s1y += a.y; s2x += a.z; s2y += a.w;
  }
  const float2* tcol = tile + c * TILEP;
  {
    const float4* e4 = (const float4*)(tcol + tt * 8 + 96);
#pragma unroll
    for (int m = 0; m < 2; ++m) {
      float4 v = e4[m];
      s1x += v.x + v.z; s1y += v.y + v.w;
      s2x = fmaf(v.x, v.x, s2x); s2x = fmaf(v.z, v.z, s2x);
      s2y = fmaf(v.y, v.y, s2y); s2y = fmaf(v.w, v.w, s2y);
    }
  }

  const int rc0 = HALF + tt * 8;                     // tile row of output 0
  const float4* xc4 = (const float4*)(tcol + rc0);
  const float4* va4 = (const float4*)(tcol + rc0 + HALF);
  const float4* vs4 = (const float4*)(tcol + rc0 - HALF);
  float2* obase = ob + (size_t)(t0 + tt * 8) * ROWF2 + c;

#pragma unroll
  for (int m = 0; m < 4; ++m) {
    float4 xcp = xc4[m];
    float4 vap = va4[m];
    float4 vsp = vs4[m];
    // output row 2m (uses window state as-is)
    {
      float mx = s1x * C1, my = s1y * C1;
      float vx = fmaf(-s1x, mx, s2x) * C2;
      float vy = fmaf(-s1y, my, s2y) * C2;
      float rx = fast_rsqrt(fmaxf(vx, 1e-30f));
      float ry = fast_rsqrt(fmaxf(vy, 1e-30f));
      obase[(2 * m) * ROWF2] = make_float2((xcp.x - mx) * rx, (xcp.y - my) * ry);
    }
    s1x += vap.x - vsp.x; s1y += vap.y - vsp.y;
    s2x = fmaf(vap.x, vap.x, s2x); s2x = fmaf(-vsp.x, vsp.x, s2x);
    s2y = fmaf(vap.y, vap.y, s2y); s2y = fmaf(-vsp.y, vsp.y, s2y);
    // output row 2m+1
    {
      float mx = s1x * C1, my = s1y * C1;
      float vx = fmaf(-s1x, mx, s2x) * C2;
      float vy = fmaf(-s1y, my, s2y) * C2;
      float rx = fast_rsqrt(fmaxf(vx, 1e-30f));
      float ry = fast_rsqrt(fmaxf(vy, 1e-30f));
      obase[(2 * m + 1) * ROWF2] = make_float2((xcp.z - mx) * rx, (xcp.w - my) * ry);
    }
    s1x += vap.z - vsp.z; s1y += vap.w - vsp.w;
    s2x = fmaf(vap.z, vap.z, s2x); s2x = fmaf(-vsp.z, vsp.z, s2x);
    s2y = fmaf(vap.w, vap.w, s2y); s2y = fmaf(-vsp.w, vsp.w, s2y);
  }
}

}  // namespace

extern "C" void kernel_launch(void* const* d_in, const int* in_sizes, int n_in,
                              void* d_out, int out_size, void* d_ws, size_t ws_size,
                              hipStream_t stream) {
  (void)in_sizes; (void)n_in; (void)out_size; (void)d_ws; (void)ws_size;
  const float2* x = (const float2*)d_in[0];
  float2* o = (float2*)d_out;
  constexpr int blocks = Bn * NTC * DGn;             // 5120
  man_kernel<<<blocks, BLK, 0, stream>>>(x, o);
}